// Round 1
// baseline (351.321 us; speedup 1.0000x reference)
//
#include <hip/hip_runtime.h>
#include <cmath>

#define NB 32
#define NS 256
#define NT 64
#define START_TAG 62
#define STOP_TAG 63

// ws layout (floats): ws[0] = gold score sum, ws[1] = all-paths score sum

__global__ __launch_bounds__(256) void gold_kernel(
    const float* __restrict__ feat, const int* __restrict__ targets,
    const int* __restrict__ lengths, float* __restrict__ ws) {
  int idx = blockIdx.x * 256 + threadIdx.x;   // 0 .. NB*NS-1
  int b = idx >> 8;                            // NS == 256
  int s = idx & 255;
  float v = 0.0f;
  if (s < lengths[b]) {
    int tgt = targets[idx];
    v = feat[(size_t)idx * (NT * NT) + tgt];
  }
  // wave-64 reduction
  #pragma unroll
  for (int off = 32; off; off >>= 1) v += __shfl_down(v, off);
  if ((threadIdx.x & 63) == 0) atomicAdd(&ws[0], v);
}

__global__ __launch_bounds__(256) void forward_kernel(
    const float* __restrict__ feat, const int* __restrict__ lengths,
    float* __restrict__ ws) {
  const int b   = blockIdx.x;
  const int tid = threadIdx.x;
  const int j   = tid & 63;   // output tag column
  const int q   = tid >> 6;   // wave id, handles i in [16q, 16q+16)
  const int i0  = q * 16;

  __shared__ float s_scores[NT];
  __shared__ float s_pm[4][NT];
  __shared__ float s_ps[4][NT];

  const float* fb = feat + (size_t)b * NS * NT * NT;
  const int len = lengths[b];

  if (q == 0) s_scores[j] = fb[START_TAG * NT + j];  // features[b,0,62,:]
  __syncthreads();

  // prefetch t = 1
  float f[16];
  if (1 < len) {
    const float* p = fb + (size_t)1 * NT * NT + i0 * NT + j;
    #pragma unroll
    for (int r = 0; r < 16; ++r) f[r] = p[r * NT];
  }

  for (int t = 1; t < len; ++t) {
    float cur[16];
    #pragma unroll
    for (int r = 0; r < 16; ++r) cur[r] = f[r];
    // prefetch t+1
    if (t + 1 < len) {
      const float* p = fb + (size_t)(t + 1) * NT * NT + i0 * NT + j;
      #pragma unroll
      for (int r = 0; r < 16; ++r) f[r] = p[r * NT];
    }
    // partial logsumexp over this wave's 16 source tags
    float vals[16];
    float m = -INFINITY;
    #pragma unroll
    for (int r = 0; r < 16; ++r) {
      vals[r] = cur[r] + s_scores[i0 + r];
      m = fmaxf(m, vals[r]);
    }
    float ssum = 0.0f;
    #pragma unroll
    for (int r = 0; r < 16; ++r) ssum += __expf(vals[r] - m);
    s_pm[q][j] = m;
    s_ps[q][j] = ssum;
    __syncthreads();
    if (q == 0) {
      float m0 = s_pm[0][j], m1 = s_pm[1][j], m2 = s_pm[2][j], m3 = s_pm[3][j];
      float mm = fmaxf(fmaxf(m0, m1), fmaxf(m2, m3));
      float ss = s_ps[0][j] * __expf(m0 - mm) + s_ps[1][j] * __expf(m1 - mm) +
                 s_ps[2][j] * __expf(m2 - mm) + s_ps[3][j] * __expf(m3 - mm);
      s_scores[j] = mm + __logf(ss);
    }
    __syncthreads();
  }

  if (tid == 0) atomicAdd(&ws[1], s_scores[STOP_TAG]);
}

__global__ void finalize_kernel(const float* __restrict__ ws,
                                float* __restrict__ out) {
  out[0] = (ws[1] - ws[0]) * (1.0f / (float)NB);
}

extern "C" void kernel_launch(void* const* d_in, const int* in_sizes, int n_in,
                              void* d_out, int out_size, void* d_ws, size_t ws_size,
                              hipStream_t stream) {
  const float* feat    = (const float*)d_in[0];
  const int*   targets = (const int*)d_in[1];
  const int*   lengths = (const int*)d_in[2];
  float* ws  = (float*)d_ws;
  float* out = (float*)d_out;

  hipMemsetAsync(d_ws, 0, 2 * sizeof(float), stream);
  gold_kernel<<<NB, 256, 0, stream>>>(feat, targets, lengths, ws);
  forward_kernel<<<NB, 256, 0, stream>>>(feat, lengths, ws);
  finalize_kernel<<<1, 1, 0, stream>>>(ws, out);
}